// Round 1
// baseline (358.558 us; speedup 1.0000x reference)
//
#include <hip/hip_runtime.h>

#define DEV __device__ __forceinline__

// quantize(x,4): clip to [-1, 0.875], round-half-even to multiples of 1/8
DEV float qact(float x, float a, float b) {
    float y = fmaf(x, a, b);                 // folded BN (a=1,b=0 for layer 1)
    y = fminf(fmaxf(y, -1.0f), 0.875f);      // clip (subsumes htanh)
    return rintf(y * 8.0f) * 0.125f;
}
DEV float qwt(float w) {
    float y = fminf(fmaxf(w, -1.0f), 0.875f);
    return rintf(y * 8.0f) * 0.125f;
}

// ---------------------------------------------------------------------------
// Generic 1-D strided conv (stride 2, VALID) with on-the-fly input transform
// quantize(a*x+b), quantized weights in LDS, int16 (x64 fixed point) output,
// per-block per-channel sum/sumsq partials for BN stats.
// ---------------------------------------------------------------------------
template<int CIN, int COUT, int K, int LIN, int LOUT, int P, bool IN_SHORT, bool HAS_TR>
__global__ __launch_bounds__(256) void conv_k(
    const void* __restrict__ in_, const float* __restrict__ w,
    const float* __restrict__ tr, short* __restrict__ out,
    float* __restrict__ partial, int B)
{
    constexpr int KP   = (K + 3) & ~3;          // pad taps to multiple of 4
    constexpr int NV   = KP + 2 * (P - 1);      // input window regs per ci
    constexpr int LO_P = (LOUT + P - 1) / P;    // position-groups per row

    __shared__ __align__(16) float wq[COUT * CIN * KP];
    __shared__ float ts[CIN], tb[CIN];
    __shared__ float red[4][2 * COUT];

    const int tid = threadIdx.x;

    for (int i = tid; i < COUT * CIN * KP; i += 256) {
        int k = i % KP, ck = i / KP;
        int ci = ck % CIN, co = ck / CIN;
        wq[i] = (k < K) ? qwt(w[(co * CIN + ci) * K + k]) : 0.0f;
    }
    if (tid < CIN) {
        ts[tid] = HAS_TR ? tr[tid]       : 1.0f;
        tb[tid] = HAS_TR ? tr[CIN + tid] : 0.0f;
    }
    __syncthreads();

    float tsum[COUT], tsq[COUT];
#pragma unroll
    for (int c = 0; c < COUT; c++) { tsum[c] = 0.f; tsq[c] = 0.f; }

    const int total = B * LO_P;
#pragma unroll 1
    for (int g = blockIdx.x * 256 + tid; g < total; g += gridDim.x * 256) {
        int b  = g / LO_P;
        int l0 = (g - b * LO_P) * P;
        int pact = LOUT - l0; if (pact > P) pact = P;
        int nva  = K + 2 * (pact - 1);

        float acc[COUT][P];
#pragma unroll
        for (int c = 0; c < COUT; c++) {
#pragma unroll
            for (int p = 0; p < P; p++) acc[c][p] = 0.f;
        }

        const size_t rowbase = (size_t)b * CIN * LIN + 2 * l0;

#pragma unroll 1
        for (int ci = 0; ci < CIN; ci++) {
            float vv[NV];
#pragma unroll
            for (int j = 0; j < NV; j++) {
                float r = 0.f;
                if (j < nva) {
                    float raw;
                    if constexpr (IN_SHORT)
                        raw = (float)(((const short*)in_)[rowbase + (size_t)ci * LIN + j]) * 0.015625f;
                    else
                        raw = ((const float*)in_)[rowbase + (size_t)ci * LIN + j];
                    r = qact(raw, ts[ci], tb[ci]);
                }
                vv[j] = r;
            }
            const float* wrow = &wq[ci * KP];
#pragma unroll
            for (int co = 0; co < COUT; co++) {
                const float4* w4 = (const float4*)&wrow[co * CIN * KP];
#pragma unroll
                for (int c4 = 0; c4 < KP / 4; c4++) {
                    float4 wv = w4[c4];
#pragma unroll
                    for (int p = 0; p < P; p++) {
                        acc[co][p] = fmaf(vv[2 * p + 4 * c4 + 0], wv.x, acc[co][p]);
                        acc[co][p] = fmaf(vv[2 * p + 4 * c4 + 1], wv.y, acc[co][p]);
                        acc[co][p] = fmaf(vv[2 * p + 4 * c4 + 2], wv.z, acc[co][p]);
                        acc[co][p] = fmaf(vv[2 * p + 4 * c4 + 3], wv.w, acc[co][p]);
                    }
                }
            }
        }

        const size_t ob = (size_t)b * COUT * LOUT + l0;
#pragma unroll
        for (int co = 0; co < COUT; co++) {
#pragma unroll
            for (int p = 0; p < P; p++) {
                if (p < pact) {
                    float v = acc[co][p];
                    out[ob + (size_t)co * LOUT + p] = (short)__float2int_rn(v * 64.0f);
                    tsum[co] += v;
                    tsq[co]   = fmaf(v, v, tsq[co]);
                }
            }
        }
    }

    const int lane = tid & 63, wid = tid >> 6;
#pragma unroll
    for (int co = 0; co < COUT; co++) {
        float s = tsum[co], q = tsq[co];
        for (int off = 32; off > 0; off >>= 1) {
            s += __shfl_down(s, off, 64);
            q += __shfl_down(q, off, 64);
        }
        if (lane == 0) { red[wid][2 * co] = s; red[wid][2 * co + 1] = q; }
    }
    __syncthreads();
    if (tid < 2 * COUT) {
        float v = red[0][tid] + red[1][tid] + red[2][tid] + red[3][tid];
        partial[(size_t)blockIdx.x * (2 * COUT) + tid] = v;
    }
}

// ---------------------------------------------------------------------------
// Finalize BN stats: one block per channel; reduce G partials (double),
// write folded scale/shift: y = scale*x + shift
// ---------------------------------------------------------------------------
__global__ __launch_bounds__(256) void finalize_k(
    const float* __restrict__ partial, int G, int C, double N,
    const float* __restrict__ gamma, const float* __restrict__ beta,
    float* __restrict__ trout)
{
    const int c = blockIdx.x;
    double s = 0.0, q = 0.0;
    for (int g = threadIdx.x; g < G; g += 256) {
        s += (double)partial[(size_t)g * 2 * C + 2 * c];
        q += (double)partial[(size_t)g * 2 * C + 2 * c + 1];
    }
    for (int off = 32; off > 0; off >>= 1) {
        s += __shfl_down(s, off, 64);
        q += __shfl_down(q, off, 64);
    }
    __shared__ double rs[4], rq[4];
    int lane = threadIdx.x & 63, wid = threadIdx.x >> 6;
    if (lane == 0) { rs[wid] = s; rq[wid] = q; }
    __syncthreads();
    if (threadIdx.x == 0) {
        double S = rs[0] + rs[1] + rs[2] + rs[3];
        double Q = rq[0] + rq[1] + rq[2] + rq[3];
        double mean = S / N;
        double var  = Q / N - mean * mean;
        double inv  = 1.0 / sqrt(var + 1e-5);
        double sc   = (double)gamma[c] * inv;
        trout[c]     = (float)sc;
        trout[C + c] = (float)((double)beta[c] - mean * sc);
    }
}

// ---------------------------------------------------------------------------
// FC1: (B,740)x(10,740)^T, one wave per row; weights quantized in LDS.
// ---------------------------------------------------------------------------
__global__ __launch_bounds__(256) void fc1_k(
    const short* __restrict__ y5, const float* __restrict__ fw1,
    const float* __restrict__ tr, float* __restrict__ z1,
    float* __restrict__ partial, int B)
{
    __shared__ float wq[7400];
    __shared__ float ts[20], tb[20];
    __shared__ float red[4][20];
    const int tid = threadIdx.x;
    for (int i = tid; i < 7400; i += 256) wq[i] = qwt(fw1[i]);
    if (tid < 20) { ts[tid] = tr[tid]; tb[tid] = tr[20 + tid]; }
    __syncthreads();

    const int lane = tid & 63, wid = tid >> 6;
    float tsum[10], tsq[10];
#pragma unroll
    for (int j = 0; j < 10; j++) { tsum[j] = 0.f; tsq[j] = 0.f; }

#pragma unroll 1
    for (int r = blockIdx.x * 4 + wid; r < B; r += gridDim.x * 4) {
        const short* xr = y5 + (size_t)r * 740;
        float acc[10];
#pragma unroll
        for (int j = 0; j < 10; j++) acc[j] = 0.f;
#pragma unroll 1
        for (int f = lane; f < 740; f += 64) {
            int c = f / 37;                         // channel-major flatten
            float x = qact((float)xr[f] * 0.015625f, ts[c], tb[c]);
#pragma unroll
            for (int j = 0; j < 10; j++) acc[j] = fmaf(x, wq[j * 740 + f], acc[j]);
        }
#pragma unroll
        for (int j = 0; j < 10; j++) {
            float v = acc[j];
            for (int off = 1; off < 64; off <<= 1) v += __shfl_xor(v, off, 64);
            tsum[j] += v; tsq[j] = fmaf(v, v, tsq[j]);
            if (lane == j) z1[(size_t)r * 10 + j] = v;
        }
    }
    if (lane == 0) {
#pragma unroll
        for (int j = 0; j < 10; j++) { red[wid][2 * j] = tsum[j]; red[wid][2 * j + 1] = tsq[j]; }
    }
    __syncthreads();
    if (tid < 20) {
        float v = red[0][tid] + red[1][tid] + red[2][tid] + red[3][tid];
        partial[(size_t)blockIdx.x * 20 + tid] = v;
    }
}

// ---------------------------------------------------------------------------
// FC2: (B,10)x(2,10)^T, one thread per row.
// ---------------------------------------------------------------------------
__global__ __launch_bounds__(256) void fc2_k(
    const float* __restrict__ z1, const float* __restrict__ fw2,
    const float* __restrict__ tr, float* __restrict__ z2,
    float* __restrict__ partial, int B)
{
    __shared__ float wq[20], ts[10], tb[10];
    __shared__ float red[4][4];
    const int tid = threadIdx.x;
    if (tid < 20) wq[tid] = qwt(fw2[tid]);
    if (tid < 10) { ts[tid] = tr[tid]; tb[tid] = tr[10 + tid]; }
    __syncthreads();

    float s0 = 0.f, q0 = 0.f, s1 = 0.f, q1 = 0.f;
    const int r = blockIdx.x * 256 + tid;
    if (r < B) {
        float a0 = 0.f, a1 = 0.f;
#pragma unroll
        for (int i = 0; i < 10; i++) {
            float x = qact(z1[(size_t)r * 10 + i], ts[i], tb[i]);
            a0 = fmaf(x, wq[i], a0);
            a1 = fmaf(x, wq[10 + i], a1);
        }
        z2[(size_t)r * 2]     = a0;
        z2[(size_t)r * 2 + 1] = a1;
        s0 = a0; q0 = a0 * a0; s1 = a1; q1 = a1 * a1;
    }
    const int lane = tid & 63, wid = tid >> 6;
    for (int off = 32; off > 0; off >>= 1) {
        s0 += __shfl_down(s0, off, 64); q0 += __shfl_down(q0, off, 64);
        s1 += __shfl_down(s1, off, 64); q1 += __shfl_down(q1, off, 64);
    }
    if (lane == 0) { red[wid][0] = s0; red[wid][1] = q0; red[wid][2] = s1; red[wid][3] = q1; }
    __syncthreads();
    if (tid < 4) {
        float v = red[0][tid] + red[1][tid] + red[2][tid] + red[3][tid];
        partial[(size_t)blockIdx.x * 4 + tid] = v;
    }
}

__global__ __launch_bounds__(256) void apply_k(
    const float* __restrict__ z2, const float* __restrict__ tr,
    float* __restrict__ out, int n)
{
    int i = blockIdx.x * 256 + threadIdx.x;
    if (i < n) {
        int c = i & 1;
        out[i] = fmaf(z2[i], tr[c], tr[2 + c]);
    }
}

// ---------------------------------------------------------------------------
extern "C" void kernel_launch(void* const* d_in, const int* in_sizes, int n_in,
                              void* d_out, int out_size, void* d_ws, size_t ws_size,
                              hipStream_t stream)
{
    const float* x   = (const float*)d_in[0];
    const float* w1  = (const float*)d_in[1];
    const float* w2  = (const float*)d_in[2];
    const float* w3  = (const float*)d_in[3];
    const float* w4  = (const float*)d_in[4];
    const float* w5  = (const float*)d_in[5];
    const float* fw1 = (const float*)d_in[6];
    const float* fw2 = (const float*)d_in[7];
    // dict order interleaves g_i, b_i
    const float *g[7], *bb[7];
    for (int i = 0; i < 7; i++) { g[i] = (const float*)d_in[8 + 2 * i]; bb[i] = (const float*)d_in[9 + 2 * i]; }

    char* ws = (char*)d_ws;
    size_t off = 0;
    auto alloc = [&](size_t bytes) -> void* {
        void* p = ws + off;
        off += (bytes + 255) & ~(size_t)255;
        return p;
    };
    short* SA      = (short*)alloc((size_t)15310848 * 2);   // y1 / y3 / y5
    short* SB      = (short*)alloc((size_t)12697600 * 2);   // y2 / y4
    float* z1      = (float*)alloc((size_t)81920 * 4);
    float* z2      = (float*)alloc((size_t)16384 * 4);
    float* partial = (float*)alloc((size_t)81920 * 4);
    float* tr2 = (float*)alloc(256); float* tr3 = (float*)alloc(256);
    float* tr4 = (float*)alloc(256); float* tr5 = (float*)alloc(256);
    float* tr6 = (float*)alloc(256); float* tr7 = (float*)alloc(256);
    float* tr8 = (float*)alloc(256);

    const int B = 8192;
    auto gridFor = [](int total) { int gr = (total + 255) / 256; return gr > 2048 ? 2048 : gr; };

    // conv1: (B,1,1250) -> (B,3,623)
    {
        int grid = gridFor(B * ((623 + 1) / 2));
        conv_k<1, 3, 6, 1250, 623, 2, false, false><<<grid, 256, 0, stream>>>(x, w1, nullptr, SA, partial, B);
        finalize_k<<<3, 256, 0, stream>>>(partial, grid, 3, (double)B * 623.0, g[0], bb[0], tr2);
    }
    // conv2: (B,3,623) -> (B,5,310)
    {
        int grid = gridFor(B * ((310 + 1) / 2));
        conv_k<3, 5, 5, 623, 310, 2, true, true><<<grid, 256, 0, stream>>>(SA, w2, tr2, SB, partial, B);
        finalize_k<<<5, 256, 0, stream>>>(partial, grid, 5, (double)B * 310.0, g[1], bb[1], tr3);
    }
    // conv3: (B,5,310) -> (B,10,154)
    {
        int grid = gridFor(B * ((154 + 1) / 2));
        conv_k<5, 10, 4, 310, 154, 2, true, true><<<grid, 256, 0, stream>>>(SB, w3, tr3, SA, partial, B);
        finalize_k<<<10, 256, 0, stream>>>(partial, grid, 10, (double)B * 154.0, g[2], bb[2], tr4);
    }
    // conv4: (B,10,154) -> (B,20,76)
    {
        int grid = gridFor(B * ((76 + 1) / 2));
        conv_k<10, 20, 4, 154, 76, 2, true, true><<<grid, 256, 0, stream>>>(SA, w4, tr4, SB, partial, B);
        finalize_k<<<20, 256, 0, stream>>>(partial, grid, 20, (double)B * 76.0, g[3], bb[3], tr5);
    }
    // conv5: (B,20,76) -> (B,20,37)
    {
        int grid = gridFor(B * ((37 + 1) / 2));
        conv_k<20, 20, 4, 76, 37, 2, true, true><<<grid, 256, 0, stream>>>(SB, w5, tr5, SA, partial, B);
        finalize_k<<<20, 256, 0, stream>>>(partial, grid, 20, (double)B * 37.0, g[4], bb[4], tr6);
    }
    // fc1: (B,740) @ (10,740)^T
    {
        int grid = 512;
        fc1_k<<<grid, 256, 0, stream>>>(SA, fw1, tr6, z1, partial, B);
        finalize_k<<<10, 256, 0, stream>>>(partial, grid, 10, (double)B, g[5], bb[5], tr7);
    }
    // fc2: (B,10) @ (2,10)^T
    {
        int grid = 32;
        fc2_k<<<grid, 256, 0, stream>>>(z1, fw2, tr7, z2, partial, B);
        finalize_k<<<2, 256, 0, stream>>>(partial, grid, 2, (double)B, g[6], bb[6], tr8);
    }
    // final BN apply -> d_out
    apply_k<<<64, 256, 0, stream>>>(z2, tr8, (float*)d_out, out_size);
}

// Round 2
// 320.474 us; speedup vs baseline: 1.1188x; 1.1188x over previous
//
#include <hip/hip_runtime.h>

#define DEV __device__ __forceinline__

// quantize weight to multiples of 1/8 in [-1, 0.875]
DEV float qwt(float w) {
    float y = fminf(fmaxf(w, -1.0f), 0.875f);
    return rintf(y * 8.0f) * 0.125f;
}
// quantize(a*x+b) -> integer in [-8,7] (value*8), exact
DEV int q8i(float x, float a, float b) {
    float y = fmaf(x, a, b);
    y = fminf(fmaxf(y, -1.0f), 0.875f);
    return (int)rintf(y * 8.0f);
}
// full transform for fc layers
DEV float qact(float x, float a, float b) {
    float y = fmaf(x, a, b);
    y = fminf(fmaxf(y, -1.0f), 0.875f);
    return rintf(y * 8.0f) * 0.125f;
}

// ---------------------------------------------------------------------------
// LDS-staged 1-D strided conv (stride 2, VALID).
// Block stages R rows (CIN x LINP shorts, x64 fixed point) -> int8 (x8) LDS,
// applying quantize(a*x+b) once per element. Compute threads slide windows
// from LDS, FMA against /8-scaled quantized weights (float4 + remainder),
// write int16 (x64) to padded global rows, accumulate BN sum/sumsq partials.
// ---------------------------------------------------------------------------
template<int CIN,int COUT,int K,int LIN,int LINP,int LOUT,int LOUTP,int P,int R,bool IN_FLOAT>
__global__ __launch_bounds__(256) void conv_k(
    const void* __restrict__ in_, const float* __restrict__ w,
    const float* __restrict__ tr, short* __restrict__ out,
    float* __restrict__ partial, int B, int numTiles)
{
    constexpr int KP4 = (K + 3) & ~3;      // weight row stride (16B aligned)
    constexpr int K4  = K & ~3;            // taps handled by float4 chunks
    constexpr int KR  = K - K4;            // remainder taps
    constexpr int NV  = K + 2 * (P - 1);   // window regs
    constexpr int LO_P = (LOUT + P - 1) / P;
    constexpr int GROUPS = R * LO_P;

    __shared__ __align__(16) signed char smem[R * CIN * LINP + 16];
    __shared__ __align__(16) float wq[COUT * CIN * KP4];
    __shared__ float ts[CIN], tb[CIN];
    __shared__ float red[4][2 * COUT];

    const int tid = threadIdx.x;

    for (int i = tid; i < COUT * CIN * KP4; i += 256) {
        int k = i % KP4; int ck = i / KP4;
        int ci = ck % CIN; int co = ck / CIN;
        wq[i] = (k < K) ? qwt(w[(co * CIN + ci) * K + k]) * 0.125f : 0.0f;
    }
    if constexpr (!IN_FLOAT) {
        if (tid < CIN) {
            ts[tid] = tr[tid] * 0.015625f;   // fold /64 of int16 storage
            tb[tid] = tr[CIN + tid];
        }
    }

    float tsum[COUT], tsq[COUT];
#pragma unroll
    for (int c = 0; c < COUT; c++) { tsum[c] = 0.f; tsq[c] = 0.f; }

    for (int tile = blockIdx.x; tile < numTiles; tile += gridDim.x) {
        const int r0   = tile * R;
        const int rcnt = min(R, B - r0);
        __syncthreads();

        // ---- stage: global -> quantized int8 LDS ----
        if constexpr (IN_FLOAT) {
            constexpr int CH = LIN / 2;                     // float2 chunks/row
            const float2* gp = (const float2*)in_;
            for (int c = tid; c < rcnt * CH; c += 256) {
                int r = c / CH, rem = c - r * CH;
                float2 v = gp[(size_t)(r0 + r) * CH + rem];
                int b0 = q8i(v.x, 1.f, 0.f) & 0xff;
                int b1 = q8i(v.y, 1.f, 0.f) & 0xff;
                *(unsigned short*)(smem + r * LINP + rem * 2) =
                    (unsigned short)(b0 | (b1 << 8));
            }
        } else {
            constexpr int CH  = CIN * LINP / 8;             // int4 chunks/row
            constexpr int CHC = LINP / 8;
            const int4* gp = (const int4*)((const short*)in_ + (size_t)r0 * CIN * LINP);
            for (int c = tid; c < rcnt * CH; c += 256) {
                int r = c / CH, rem = c - r * CH;
                int ci = rem / CHC;
                float a = ts[ci], bo = tb[ci];
                int4 v = gp[c];
                int vs[4] = { v.x, v.y, v.z, v.w };
                unsigned pk[2];
#pragma unroll
                for (int u = 0; u < 2; u++) {
                    unsigned pp = 0;
#pragma unroll
                    for (int j = 0; j < 2; j++) {
                        int word = vs[u * 2 + j];
                        int b0 = q8i((float)(short)(word & 0xffff), a, bo) & 0xff;
                        int b1 = q8i((float)(short)(word >> 16),    a, bo) & 0xff;
                        pp |= (unsigned)(b0 | (b1 << 8)) << (16 * j);
                    }
                    pk[u] = pp;
                }
                ((uint2*)smem)[c] = make_uint2(pk[0], pk[1]);
            }
        }
        __syncthreads();

        // ---- compute ----
#pragma unroll 1
        for (int g = tid; g < GROUPS; g += 256) {
            int r = g / LO_P;
            if (r >= rcnt) continue;
            int l0   = (g - r * LO_P) * P;
            int pact = min(P, LOUT - l0);

            float acc[COUT][P];
#pragma unroll
            for (int co = 0; co < COUT; co++)
#pragma unroll
                for (int p = 0; p < P; p++) acc[co][p] = 0.f;

            const int ibase = r * CIN * LINP + 2 * l0;
#pragma unroll 1
            for (int ci = 0; ci < CIN; ci++) {
                float vv[NV];
#pragma unroll
                for (int j = 0; j < NV; j++)
                    vv[j] = (float)smem[ibase + ci * LINP + j];  // garbage past row end is masked at store
#pragma unroll
                for (int co = 0; co < COUT; co++) {
                    const float* wrow = &wq[(co * CIN + ci) * KP4];
#pragma unroll
                    for (int c4 = 0; c4 < K4 / 4; c4++) {
                        float4 wv = *(const float4*)(wrow + 4 * c4);
#pragma unroll
                        for (int p = 0; p < P; p++) {
                            acc[co][p] = fmaf(vv[2*p + 4*c4 + 0], wv.x, acc[co][p]);
                            acc[co][p] = fmaf(vv[2*p + 4*c4 + 1], wv.y, acc[co][p]);
                            acc[co][p] = fmaf(vv[2*p + 4*c4 + 2], wv.z, acc[co][p]);
                            acc[co][p] = fmaf(vv[2*p + 4*c4 + 3], wv.w, acc[co][p]);
                        }
                    }
#pragma unroll
                    for (int u = 0; u < KR; u++) {
                        float wsc = wrow[K4 + u];
#pragma unroll
                        for (int p = 0; p < P; p++)
                            acc[co][p] = fmaf(vv[2*p + K4 + u], wsc, acc[co][p]);
                    }
                }
            }

            const size_t ob = (size_t)(r0 + r) * COUT * LOUTP + l0;
#pragma unroll
            for (int co = 0; co < COUT; co++) {
                if (pact == P) {
                    short tmp[P];
#pragma unroll
                    for (int p = 0; p < P; p++) {
                        float v = acc[co][p];
                        tmp[p] = (short)__float2int_rn(v * 64.0f);
                        tsum[co] += v;
                        tsq[co]   = fmaf(v, v, tsq[co]);
                    }
                    short* op = &out[ob + (size_t)co * LOUTP];
                    if constexpr (P == 2) {
                        *(short2*)op = make_short2(tmp[0], tmp[1]);
                    } else if constexpr (P == 4) {
                        *(short4*)op = make_short4(tmp[0], tmp[1], tmp[2], tmp[3]);
                    } else if constexpr (P == 8) {
                        *(short4*)op       = make_short4(tmp[0], tmp[1], tmp[2], tmp[3]);
                        *(short4*)(op + 4) = make_short4(tmp[4], tmp[5], tmp[6], tmp[7]);
                    } else {
#pragma unroll
                        for (int p = 0; p < P; p++) op[p] = tmp[p];
                    }
                } else {
#pragma unroll
                    for (int p = 0; p < P; p++) {
                        if (p < pact) {
                            float v = acc[co][p];
                            out[ob + (size_t)co * LOUTP + p] = (short)__float2int_rn(v * 64.0f);
                            tsum[co] += v;
                            tsq[co]   = fmaf(v, v, tsq[co]);
                        }
                    }
                }
            }
        }
    }

    const int lane = tid & 63, wid = tid >> 6;
#pragma unroll
    for (int co = 0; co < COUT; co++) {
        float s = tsum[co], q = tsq[co];
        for (int off = 32; off > 0; off >>= 1) {
            s += __shfl_down(s, off, 64);
            q += __shfl_down(q, off, 64);
        }
        if (lane == 0) { red[wid][2 * co] = s; red[wid][2 * co + 1] = q; }
    }
    __syncthreads();
    if (tid < 2 * COUT) {
        float v = red[0][tid] + red[1][tid] + red[2][tid] + red[3][tid];
        partial[(size_t)blockIdx.x * (2 * COUT) + tid] = v;
    }
}

// ---------------------------------------------------------------------------
// Finalize BN stats: one block per channel; reduce G partials (double),
// write folded scale/shift: y = scale*x + shift
// ---------------------------------------------------------------------------
__global__ __launch_bounds__(256) void finalize_k(
    const float* __restrict__ partial, int G, int C, double N,
    const float* __restrict__ gamma, const float* __restrict__ beta,
    float* __restrict__ trout)
{
    const int c = blockIdx.x;
    double s = 0.0, q = 0.0;
    for (int g = threadIdx.x; g < G; g += 256) {
        s += (double)partial[(size_t)g * 2 * C + 2 * c];
        q += (double)partial[(size_t)g * 2 * C + 2 * c + 1];
    }
    for (int off = 32; off > 0; off >>= 1) {
        s += __shfl_down(s, off, 64);
        q += __shfl_down(q, off, 64);
    }
    __shared__ double rs[4], rq[4];
    int lane = threadIdx.x & 63, wid = threadIdx.x >> 6;
    if (lane == 0) { rs[wid] = s; rq[wid] = q; }
    __syncthreads();
    if (threadIdx.x == 0) {
        double S = rs[0] + rs[1] + rs[2] + rs[3];
        double Q = rq[0] + rq[1] + rq[2] + rq[3];
        double mean = S / N;
        double var  = Q / N - mean * mean;
        double inv  = 1.0 / sqrt(var + 1e-5);
        double sc   = (double)gamma[c] * inv;
        trout[c]     = (float)sc;
        trout[C + c] = (float)((double)beta[c] - mean * sc);
    }
}

// ---------------------------------------------------------------------------
// FC1: (B,740)x(10,740)^T, one wave per row; y5 is (B,20,40) padded shorts.
// ---------------------------------------------------------------------------
__global__ __launch_bounds__(256) void fc1_k(
    const short* __restrict__ y5, const float* __restrict__ fw1,
    const float* __restrict__ tr, float* __restrict__ z1,
    float* __restrict__ partial, int B)
{
    __shared__ float wq[7400];
    __shared__ float ts[20], tb[20];
    __shared__ float red[4][20];
    const int tid = threadIdx.x;
    for (int i = tid; i < 7400; i += 256) wq[i] = qwt(fw1[i]);
    if (tid < 20) { ts[tid] = tr[tid]; tb[tid] = tr[20 + tid]; }
    __syncthreads();

    const int lane = tid & 63, wid = tid >> 6;
    float tsum[10], tsq[10];
#pragma unroll
    for (int j = 0; j < 10; j++) { tsum[j] = 0.f; tsq[j] = 0.f; }

#pragma unroll 1
    for (int r = blockIdx.x * 4 + wid; r < B; r += gridDim.x * 4) {
        const short* xr = y5 + (size_t)r * 800;   // 20 ch x 40 padded
        float acc[10];
#pragma unroll
        for (int j = 0; j < 10; j++) acc[j] = 0.f;
#pragma unroll 1
        for (int f = lane; f < 740; f += 64) {
            int c = f / 37, pos = f - c * 37;     // channel-major flatten
            float x = qact((float)xr[c * 40 + pos] * 0.015625f, ts[c], tb[c]);
#pragma unroll
            for (int j = 0; j < 10; j++) acc[j] = fmaf(x, wq[j * 740 + f], acc[j]);
        }
#pragma unroll
        for (int j = 0; j < 10; j++) {
            float v = acc[j];
            for (int off = 1; off < 64; off <<= 1) v += __shfl_xor(v, off, 64);
            tsum[j] += v; tsq[j] = fmaf(v, v, tsq[j]);
            if (lane == j) z1[(size_t)r * 10 + j] = v;
        }
    }
    if (lane == 0) {
#pragma unroll
        for (int j = 0; j < 10; j++) { red[wid][2 * j] = tsum[j]; red[wid][2 * j + 1] = tsq[j]; }
    }
    __syncthreads();
    if (tid < 20) {
        float v = red[0][tid] + red[1][tid] + red[2][tid] + red[3][tid];
        partial[(size_t)blockIdx.x * 20 + tid] = v;
    }
}

// ---------------------------------------------------------------------------
// FC2: (B,10)x(2,10)^T, one thread per row.
// ---------------------------------------------------------------------------
__global__ __launch_bounds__(256) void fc2_k(
    const float* __restrict__ z1, const float* __restrict__ fw2,
    const float* __restrict__ tr, float* __restrict__ z2,
    float* __restrict__ partial, int B)
{
    __shared__ float wq[20], ts[10], tb[10];
    __shared__ float red[4][4];
    const int tid = threadIdx.x;
    if (tid < 20) wq[tid] = qwt(fw2[tid]);
    if (tid < 10) { ts[tid] = tr[tid]; tb[tid] = tr[10 + tid]; }
    __syncthreads();

    float s0 = 0.f, q0 = 0.f, s1 = 0.f, q1 = 0.f;
    const int r = blockIdx.x * 256 + tid;
    if (r < B) {
        float a0 = 0.f, a1 = 0.f;
#pragma unroll
        for (int i = 0; i < 10; i++) {
            float x = qact(z1[(size_t)r * 10 + i], ts[i], tb[i]);
            a0 = fmaf(x, wq[i], a0);
            a1 = fmaf(x, wq[10 + i], a1);
        }
        z2[(size_t)r * 2]     = a0;
        z2[(size_t)r * 2 + 1] = a1;
        s0 = a0; q0 = a0 * a0; s1 = a1; q1 = a1 * a1;
    }
    const int lane = tid & 63, wid = tid >> 6;
    for (int off = 32; off > 0; off >>= 1) {
        s0 += __shfl_down(s0, off, 64); q0 += __shfl_down(q0, off, 64);
        s1 += __shfl_down(s1, off, 64); q1 += __shfl_down(q1, off, 64);
    }
    if (lane == 0) { red[wid][0] = s0; red[wid][1] = q0; red[wid][2] = s1; red[wid][3] = q1; }
    __syncthreads();
    if (tid < 4) {
        float v = red[0][tid] + red[1][tid] + red[2][tid] + red[3][tid];
        partial[(size_t)blockIdx.x * 4 + tid] = v;
    }
}

__global__ __launch_bounds__(256) void apply_k(
    const float* __restrict__ z2, const float* __restrict__ tr,
    float* __restrict__ out, int n)
{
    int i = blockIdx.x * 256 + threadIdx.x;
    if (i < n) {
        int c = i & 1;
        out[i] = fmaf(z2[i], tr[c], tr[2 + c]);
    }
}

// ---------------------------------------------------------------------------
extern "C" void kernel_launch(void* const* d_in, const int* in_sizes, int n_in,
                              void* d_out, int out_size, void* d_ws, size_t ws_size,
                              hipStream_t stream)
{
    const float* x   = (const float*)d_in[0];
    const float* w1  = (const float*)d_in[1];
    const float* w2  = (const float*)d_in[2];
    const float* w3  = (const float*)d_in[3];
    const float* w4  = (const float*)d_in[4];
    const float* w5  = (const float*)d_in[5];
    const float* fw1 = (const float*)d_in[6];
    const float* fw2 = (const float*)d_in[7];
    const float *g[7], *bb[7];
    for (int i = 0; i < 7; i++) { g[i] = (const float*)d_in[8 + 2 * i]; bb[i] = (const float*)d_in[9 + 2 * i]; }

    char* ws = (char*)d_ws;
    size_t off = 0;
    auto alloc = [&](size_t bytes) -> void* {
        void* p = ws + off;
        off += (bytes + 255) & ~(size_t)255;
        return p;
    };
    // padded intermediates (shorts, x64 fixed point):
    // y1 (B,3,624) / y3 (B,10,160) / y5 (B,20,40) share SA; y2 (B,5,312) / y4 (B,20,80) share SB
    short* SA      = (short*)alloc((size_t)8192 * 3 * 624 * 2);
    short* SB      = (short*)alloc((size_t)8192 * 20 * 80 * 2);
    float* z1      = (float*)alloc((size_t)81920 * 4);
    float* z2      = (float*)alloc((size_t)16384 * 4);
    float* partial = (float*)alloc((size_t)81920 * 4);
    float* tr2 = (float*)alloc(256); float* tr3 = (float*)alloc(256);
    float* tr4 = (float*)alloc(256); float* tr5 = (float*)alloc(256);
    float* tr6 = (float*)alloc(256); float* tr7 = (float*)alloc(256);
    float* tr8 = (float*)alloc(256);

    const int B = 8192;

    // conv1: (B,1,1250) f32 -> (B,3,624p) ; R=8, P=8
    {
        int nt = (B + 7) / 8;
        conv_k<1, 3, 6, 1250, 1252, 623, 624, 8, 8, true>
            <<<nt, 256, 0, stream>>>(x, w1, nullptr, SA, partial, B, nt);
        finalize_k<<<3, 256, 0, stream>>>(partial, nt, 3, (double)B * 623.0, g[0], bb[0], tr2);
    }
    // conv2: (B,3,624p) -> (B,5,312p) ; R=8, P=4
    {
        int nt = (B + 7) / 8;
        conv_k<3, 5, 5, 623, 624, 310, 312, 4, 8, false>
            <<<nt, 256, 0, stream>>>(SA, w2, tr2, SB, partial, B, nt);
        finalize_k<<<5, 256, 0, stream>>>(partial, nt, 5, (double)B * 310.0, g[1], bb[1], tr3);
    }
    // conv3: (B,5,312p) -> (B,10,160p) ; R=7, P=4
    {
        int nt = (B + 6) / 7;
        conv_k<5, 10, 4, 310, 312, 154, 160, 4, 7, false>
            <<<nt, 256, 0, stream>>>(SB, w3, tr3, SA, partial, B, nt);
        finalize_k<<<10, 256, 0, stream>>>(partial, nt, 10, (double)B * 154.0, g[2], bb[2], tr4);
    }
    // conv4: (B,10,160p) -> (B,20,80p) ; R=13, P=4
    {
        int nt = (B + 12) / 13;
        conv_k<10, 20, 4, 154, 160, 76, 80, 4, 13, false>
            <<<nt, 256, 0, stream>>>(SA, w4, tr4, SB, partial, B, nt);
        finalize_k<<<20, 256, 0, stream>>>(partial, nt, 20, (double)B * 76.0, g[3], bb[3], tr5);
    }
    // conv5: (B,20,80p) -> (B,20,40p) ; R=13, P=2
    {
        int nt = (B + 12) / 13;
        conv_k<20, 20, 4, 76, 80, 37, 40, 2, 13, false>
            <<<nt, 256, 0, stream>>>(SB, w5, tr5, SA, partial, B, nt);
        finalize_k<<<20, 256, 0, stream>>>(partial, nt, 20, (double)B * 37.0, g[4], bb[4], tr6);
    }
    // fc1: (B,740) @ (10,740)^T
    {
        int grid = 512;
        fc1_k<<<grid, 256, 0, stream>>>(SA, fw1, tr6, z1, partial, B);
        finalize_k<<<10, 256, 0, stream>>>(partial, grid, 10, (double)B, g[5], bb[5], tr7);
    }
    // fc2: (B,10) @ (2,10)^T
    {
        int grid = 32;
        fc2_k<<<grid, 256, 0, stream>>>(z1, fw2, tr7, z2, partial, B);
        finalize_k<<<2, 256, 0, stream>>>(partial, grid, 2, (double)B, g[6], bb[6], tr8);
    }
    // final BN apply -> d_out
    apply_k<<<64, 256, 0, stream>>>(z2, tr8, (float*)d_out, out_size);
}

// Round 3
// 305.816 us; speedup vs baseline: 1.1725x; 1.0479x over previous
//
#include <hip/hip_runtime.h>

#define DEV __device__ __forceinline__

// ---- quantizer helpers (exact, round-half-even matches jnp.round) ----
DEV float qwt(float w) {
    float y = fminf(fmaxf(w, -1.0f), 0.875f);
    return rintf(y * 8.0f) * 0.125f;
}
DEV int qw8i(float w) {                       // weight -> int in [-8,7]
    float y = fminf(fmaxf(w, -1.0f), 0.875f);
    return (int)rintf(y * 8.0f);
}
DEV int q8i(float x, float a, float b) {      // act -> int in [-8,7]
    float y = fmaf(x, a, b);
    y = fminf(fmaxf(y, -1.0f), 0.875f);
    return (int)rintf(y * 8.0f);
}
DEV float qact(float x, float a, float b) {
    float y = fmaf(x, a, b);
    y = fminf(fmaxf(y, -1.0f), 0.875f);
    return rintf(y * 8.0f) * 0.125f;
}

DEV int dot4(int a, int b, int c) {
#if __has_builtin(__builtin_amdgcn_sdot4)
    return __builtin_amdgcn_sdot4(a, b, c, false);
#else
    c += (int)(signed char)(a)       * (int)(signed char)(b);
    c += (int)(signed char)(a >> 8)  * (int)(signed char)(b >> 8);
    c += (int)(signed char)(a >> 16) * (int)(signed char)(b >> 16);
    c += (int)(signed char)(a >> 24) * (int)(signed char)(b >> 24);
    return c;
#endif
}
DEV unsigned alignpair(unsigned hi, unsigned lo, int bits) {
#if __has_builtin(__builtin_amdgcn_alignbit)
    return __builtin_amdgcn_alignbit(hi, lo, bits);
#else
    return bits ? ((lo >> bits) | (hi << (32 - bits))) : lo;
#endif
}

// ---------------------------------------------------------------------------
// Pack all conv weights: float OIHW -> int8x4 dwords (value*8), zero-padded
// beyond K. Layout: wq[(co*CIN+ci)*KW + j], byte u = tap 4j+u.
// ---------------------------------------------------------------------------
DEV void pack_layer(const float* w, int* o, int CIN, int COUT, int K, int t) {
    int KW = (K + 3) / 4;
    for (int i = t; i < COUT * CIN * KW; i += 256) {
        int j = i % KW, cc = i / KW;
        unsigned r = 0;
        for (int u = 0; u < 4; u++) {
            int k = 4 * j + u;
            int b = (k < K) ? (qw8i(w[cc * K + k]) & 0xff) : 0;
            r |= (unsigned)b << (8 * u);
        }
        o[i] = (int)r;
    }
}
__global__ __launch_bounds__(256) void pack_k(
    const float* w1, const float* w2, const float* w3, const float* w4, const float* w5,
    int* o1, int* o2, int* o3, int* o4, int* o5)
{
    int t = threadIdx.x;
    pack_layer(w1, o1, 1, 3, 6, t);
    pack_layer(w2, o2, 3, 5, 5, t);
    pack_layer(w3, o3, 5, 10, 4, t);
    pack_layer(w4, o4, 10, 20, 4, t);
    pack_layer(w5, o5, 20, 20, 4, t);
}

// ---------------------------------------------------------------------------
// int8/dot4 1-D strided conv (stride 2, VALID).
// Stage R rows -> int8 (x8) LDS with quantize(a*x+b) applied once per elem.
// Compute: per thread, P consecutive outputs; windows built from aligned
// dword LDS reads + alignbit; sdot4 against scalar-loaded packed weights.
// Output short = int acc (value*64, exact). BN sum/sumsq partials per block.
// ---------------------------------------------------------------------------
template<int CIN,int COUT,int K,int LINP,int LOUT,int LOUTP,int P,int R,bool IN_FLOAT,int LIN=0>
__global__ __launch_bounds__(256) void conv_k(
    const void* __restrict__ in_, const int* __restrict__ wqi,
    const float* __restrict__ tr, short* __restrict__ out,
    float* __restrict__ partial, int B)
{
    constexpr int KW   = (K + 3) / 4;
    constexpr int NE   = P + 2 * KW - 2 + 1;     // windows e[0..NE-1] (max idx (P-1)+2(KW-1))
    constexpr int ND   = (2 * (NE - 1) + 3) / 4 + 2;
    constexpr int LO_P = (LOUT + P - 1) / P;
    constexpr int GROUPS = R * LO_P;

    __shared__ __align__(16) signed char smem[R * CIN * LINP + 32];
    __shared__ float ts[CIN > 0 ? CIN : 1], tb[CIN > 0 ? CIN : 1];
    __shared__ float red[4][2 * COUT];

    const int tid = threadIdx.x;

    if constexpr (!IN_FLOAT) {
        if (tid < CIN) {
            ts[tid] = tr[tid] * 0.015625f;   // fold /64 of int16 storage
            tb[tid] = tr[CIN + tid];
        }
        __syncthreads();
    }

    const int r0   = blockIdx.x * R;
    const int rcnt = min(R, B - r0);

    // ---- stage: global -> quantized int8 LDS ----
    if constexpr (IN_FLOAT) {
        constexpr int CH = LIN / 2;
        const float2* gp = (const float2*)in_;
        for (int c = tid; c < rcnt * CH; c += 256) {
            int r = c / CH, rem = c - r * CH;
            float2 v = gp[(size_t)(r0 + r) * CH + rem];
            int b0 = q8i(v.x, 1.f, 0.f) & 0xff;
            int b1 = q8i(v.y, 1.f, 0.f) & 0xff;
            *(unsigned short*)(smem + r * LINP + rem * 2) =
                (unsigned short)(b0 | (b1 << 8));
        }
    } else {
        constexpr int CH  = CIN * LINP / 8;
        constexpr int CHC = LINP / 8;
        const int4* gp = (const int4*)((const short*)in_ + (size_t)r0 * CIN * LINP);
        for (int c = tid; c < rcnt * CH; c += 256) {
            int rem = c % CH;
            int ci = rem / CHC;
            float a = ts[ci], bo = tb[ci];
            int4 v = gp[c];
            int vs[4] = { v.x, v.y, v.z, v.w };
            unsigned pk[2];
#pragma unroll
            for (int u = 0; u < 2; u++) {
                unsigned pp = 0;
#pragma unroll
                for (int j = 0; j < 2; j++) {
                    int word = vs[u * 2 + j];
                    int b0 = q8i((float)(short)(word & 0xffff), a, bo) & 0xff;
                    int b1 = q8i((float)(short)(word >> 16),    a, bo) & 0xff;
                    pp |= (unsigned)(b0 | (b1 << 8)) << (16 * j);
                }
                pk[u] = pp;
            }
            ((uint2*)smem)[c] = make_uint2(pk[0], pk[1]);
        }
    }
    __syncthreads();

    float tsum[COUT], tsq[COUT];
#pragma unroll
    for (int c = 0; c < COUT; c++) { tsum[c] = 0.f; tsq[c] = 0.f; }

    // ---- compute ----
#pragma unroll 1
    for (int g = tid; g < GROUPS; g += 256) {
        int r = g / LO_P;
        if (r >= rcnt) continue;
        int l0   = (g - r * LO_P) * P;
        int pact = min(P, LOUT - l0);

        int acc[COUT][P];
#pragma unroll
        for (int co = 0; co < COUT; co++)
#pragma unroll
            for (int p = 0; p < P; p++) acc[co][p] = 0;

        const int ibase = r * CIN * LINP + 2 * l0;         // byte offset
        const int sh    = (P % 2 == 0) ? 0 : (ibase & 3);  // 0 or 2

        for (int ci = 0; ci < CIN; ci++) {
            const int* sp = (const int*)smem + ((ci * LINP + (ibase & ~3)) >> 2);
            int d[ND];
#pragma unroll
            for (int j = 0; j < ND; j++) d[j] = sp[j];
            int e[NE];
#pragma unroll
            for (int i = 0; i < NE; i++) {
                int off = sh + 2 * i;
                e[i] = (int)alignpair((unsigned)d[off / 4 + 1], (unsigned)d[off / 4], (off & 3) * 8);
            }
#pragma unroll
            for (int co = 0; co < COUT; co++) {
#pragma unroll
                for (int j = 0; j < KW; j++) {
                    int wv = wqi[(co * CIN + ci) * KW + j];
#pragma unroll
                    for (int p = 0; p < P; p++)
                        acc[co][p] = dot4(e[p + 2 * j], wv, acc[co][p]);
                }
            }
        }

        const size_t ob = (size_t)(r0 + r) * COUT * LOUTP + l0;
#pragma unroll
        for (int co = 0; co < COUT; co++) {
            if (pact == P) {
                short tmp[P];
#pragma unroll
                for (int p = 0; p < P; p++) {
                    tmp[p] = (short)acc[co][p];
                    float v = (float)acc[co][p] * 0.015625f;
                    tsum[co] += v;
                    tsq[co]   = fmaf(v, v, tsq[co]);
                }
                short* op = &out[ob + (size_t)co * LOUTP];
                if constexpr (P == 1) {
                    op[0] = tmp[0];
                } else if constexpr (P == 2) {
                    *(short2*)op = make_short2(tmp[0], tmp[1]);
                } else if constexpr (P == 4) {
                    *(short4*)op = make_short4(tmp[0], tmp[1], tmp[2], tmp[3]);
                } else if constexpr (P == 8) {
                    *(short4*)op       = make_short4(tmp[0], tmp[1], tmp[2], tmp[3]);
                    *(short4*)(op + 4) = make_short4(tmp[4], tmp[5], tmp[6], tmp[7]);
                }
            } else {
#pragma unroll
                for (int p = 0; p < P; p++) {
                    if (p < pact) {
                        out[ob + (size_t)co * LOUTP + p] = (short)acc[co][p];
                        float v = (float)acc[co][p] * 0.015625f;
                        tsum[co] += v;
                        tsq[co]   = fmaf(v, v, tsq[co]);
                    }
                }
            }
        }
    }

    const int lane = tid & 63, wid = tid >> 6;
#pragma unroll
    for (int co = 0; co < COUT; co++) {
        float s = tsum[co], q = tsq[co];
        for (int off = 32; off > 0; off >>= 1) {
            s += __shfl_down(s, off, 64);
            q += __shfl_down(q, off, 64);
        }
        if (lane == 0) { red[wid][2 * co] = s; red[wid][2 * co + 1] = q; }
    }
    __syncthreads();
    if (tid < 2 * COUT) {
        float v = red[0][tid] + red[1][tid] + red[2][tid] + red[3][tid];
        partial[(size_t)blockIdx.x * (2 * COUT) + tid] = v;
    }
}

// ---------------------------------------------------------------------------
// Finalize BN stats -> folded scale/shift
// ---------------------------------------------------------------------------
__global__ __launch_bounds__(256) void finalize_k(
    const float* __restrict__ partial, int G, int C, double N,
    const float* __restrict__ gamma, const float* __restrict__ beta,
    float* __restrict__ trout)
{
    const int c = blockIdx.x;
    double s = 0.0, q = 0.0;
    for (int g = threadIdx.x; g < G; g += 256) {
        s += (double)partial[(size_t)g * 2 * C + 2 * c];
        q += (double)partial[(size_t)g * 2 * C + 2 * c + 1];
    }
    for (int off = 32; off > 0; off >>= 1) {
        s += __shfl_down(s, off, 64);
        q += __shfl_down(q, off, 64);
    }
    __shared__ double rs[4], rq[4];
    int lane = threadIdx.x & 63, wid = threadIdx.x >> 6;
    if (lane == 0) { rs[wid] = s; rq[wid] = q; }
    __syncthreads();
    if (threadIdx.x == 0) {
        double S = rs[0] + rs[1] + rs[2] + rs[3];
        double Q = rq[0] + rq[1] + rq[2] + rq[3];
        double mean = S / N;
        double var  = Q / N - mean * mean;
        double inv  = 1.0 / sqrt(var + 1e-5);
        double sc   = (double)gamma[c] * inv;
        trout[c]     = (float)sc;
        trout[C + c] = (float)((double)beta[c] - mean * sc);
    }
}

// ---------------------------------------------------------------------------
// FC1: (B,740)x(10,740)^T, one wave per row; y5 is (B,20,40) padded shorts.
// ---------------------------------------------------------------------------
__global__ __launch_bounds__(256) void fc1_k(
    const short* __restrict__ y5, const float* __restrict__ fw1,
    const float* __restrict__ tr, float* __restrict__ z1,
    float* __restrict__ partial, int B)
{
    __shared__ float wq[7400];
    __shared__ float ts[20], tb[20];
    __shared__ float red[4][20];
    const int tid = threadIdx.x;
    for (int i = tid; i < 7400; i += 256) wq[i] = qwt(fw1[i]);
    if (tid < 20) { ts[tid] = tr[tid]; tb[tid] = tr[20 + tid]; }
    __syncthreads();

    const int lane = tid & 63, wid = tid >> 6;
    float tsum[10], tsq[10];
#pragma unroll
    for (int j = 0; j < 10; j++) { tsum[j] = 0.f; tsq[j] = 0.f; }

#pragma unroll 1
    for (int r = blockIdx.x * 4 + wid; r < B; r += gridDim.x * 4) {
        const short* xr = y5 + (size_t)r * 800;
        float acc[10];
#pragma unroll
        for (int j = 0; j < 10; j++) acc[j] = 0.f;
#pragma unroll 1
        for (int f = lane; f < 740; f += 64) {
            int c = f / 37, pos = f - c * 37;
            float x = qact((float)xr[c * 40 + pos] * 0.015625f, ts[c], tb[c]);
#pragma unroll
            for (int j = 0; j < 10; j++) acc[j] = fmaf(x, wq[j * 740 + f], acc[j]);
        }
#pragma unroll
        for (int j = 0; j < 10; j++) {
            float v = acc[j];
            for (int off = 1; off < 64; off <<= 1) v += __shfl_xor(v, off, 64);
            tsum[j] += v; tsq[j] = fmaf(v, v, tsq[j]);
            if (lane == j) z1[(size_t)r * 10 + j] = v;
        }
    }
    if (lane == 0) {
#pragma unroll
        for (int j = 0; j < 10; j++) { red[wid][2 * j] = tsum[j]; red[wid][2 * j + 1] = tsq[j]; }
    }
    __syncthreads();
    if (tid < 20) {
        float v = red[0][tid] + red[1][tid] + red[2][tid] + red[3][tid];
        partial[(size_t)blockIdx.x * 20 + tid] = v;
    }
}

// ---------------------------------------------------------------------------
// FC2 fused single-block: reduce fc1 partials -> tr7, compute z2 (LDS),
// z2 stats -> tr8, apply -> out.  One dispatch replaces 4.
// ---------------------------------------------------------------------------
__global__ __launch_bounds__(256) void fc2_fused_k(
    const float* __restrict__ z1, const float* __restrict__ fw2,
    const float* __restrict__ part6, int G6,
    const float* __restrict__ g6, const float* __restrict__ b6,
    const float* __restrict__ g7, const float* __restrict__ b7,
    float* __restrict__ outp, int B)
{
    __shared__ float zbuf[16384];
    __shared__ double dred[4][20];
    __shared__ double dtot[20];
    __shared__ float ts7[10], tb7[10], wq2[20];
    __shared__ float fr[4][4];
    __shared__ float tr8[4];

    const int tid = threadIdx.x;
    const int lane = tid & 63, wid = tid >> 6;

    // prologue: reduce fc1 partials (G6 x 20) in doubles
    double ls[20];
#pragma unroll
    for (int c = 0; c < 20; c++) ls[c] = 0.0;
    for (int g = tid; g < G6; g += 256) {
#pragma unroll
        for (int c = 0; c < 20; c++) ls[c] += (double)part6[(size_t)g * 20 + c];
    }
#pragma unroll
    for (int c = 0; c < 20; c++) {
        double v = ls[c];
        for (int off = 32; off > 0; off >>= 1) v += __shfl_down(v, off, 64);
        if (lane == 0) dred[wid][c] = v;
    }
    if (tid < 20) wq2[tid] = qwt(fw2[tid]);
    __syncthreads();
    if (tid < 20) dtot[tid] = dred[0][tid] + dred[1][tid] + dred[2][tid] + dred[3][tid];
    __syncthreads();
    if (tid < 10) {
        double N = (double)B;
        double mean = dtot[2 * tid] / N;
        double var  = dtot[2 * tid + 1] / N - mean * mean;
        double inv  = 1.0 / sqrt(var + 1e-5);
        double sc   = (double)g6[tid] * inv;
        ts7[tid] = (float)sc;
        tb7[tid] = (float)((double)b6[tid] - mean * sc);
    }
    __syncthreads();

    // main: z2 rows + stats
    float s0 = 0.f, q0 = 0.f, s1 = 0.f, q1 = 0.f;
#pragma unroll 1
    for (int r = tid; r < B; r += 256) {
        float a0 = 0.f, a1 = 0.f;
#pragma unroll
        for (int i = 0; i < 10; i++) {
            float x = qact(z1[(size_t)r * 10 + i], ts7[i], tb7[i]);
            a0 = fmaf(x, wq2[i], a0);
            a1 = fmaf(x, wq2[10 + i], a1);
        }
        zbuf[r * 2]     = a0;
        zbuf[r * 2 + 1] = a1;
        s0 += a0; q0 = fmaf(a0, a0, q0);
        s1 += a1; q1 = fmaf(a1, a1, q1);
    }
    for (int off = 32; off > 0; off >>= 1) {
        s0 += __shfl_down(s0, off, 64); q0 += __shfl_down(q0, off, 64);
        s1 += __shfl_down(s1, off, 64); q1 += __shfl_down(q1, off, 64);
    }
    if (lane == 0) { fr[wid][0] = s0; fr[wid][1] = q0; fr[wid][2] = s1; fr[wid][3] = q1; }
    __syncthreads();
    if (tid < 2) {
        double S = 0.0, Q = 0.0;
        for (int w = 0; w < 4; w++) { S += (double)fr[w][2 * tid]; Q += (double)fr[w][2 * tid + 1]; }
        double N = (double)B;
        double mean = S / N;
        double var  = Q / N - mean * mean;
        double inv  = 1.0 / sqrt(var + 1e-5);
        double sc   = (double)g7[tid] * inv;
        tr8[tid]     = (float)sc;
        tr8[2 + tid] = (float)((double)b7[tid] - mean * sc);
    }
    __syncthreads();
    for (int i = tid; i < 2 * B; i += 256) {
        int c = i & 1;
        outp[i] = fmaf(zbuf[i], tr8[c], tr8[2 + c]);
    }
}

// ---------------------------------------------------------------------------
extern "C" void kernel_launch(void* const* d_in, const int* in_sizes, int n_in,
                              void* d_out, int out_size, void* d_ws, size_t ws_size,
                              hipStream_t stream)
{
    const float* x   = (const float*)d_in[0];
    const float* w1  = (const float*)d_in[1];
    const float* w2  = (const float*)d_in[2];
    const float* w3  = (const float*)d_in[3];
    const float* w4  = (const float*)d_in[4];
    const float* w5  = (const float*)d_in[5];
    const float* fw1 = (const float*)d_in[6];
    const float* fw2 = (const float*)d_in[7];
    const float *g[7], *bb[7];
    for (int i = 0; i < 7; i++) { g[i] = (const float*)d_in[8 + 2 * i]; bb[i] = (const float*)d_in[9 + 2 * i]; }

    char* ws = (char*)d_ws;
    size_t off = 0;
    auto alloc = [&](size_t bytes) -> void* {
        void* p = ws + off;
        off += (bytes + 255) & ~(size_t)255;
        return p;
    };
    short* SA      = (short*)alloc((size_t)8192 * 3 * 624 * 2);   // y1 / y3 / y5
    short* SB      = (short*)alloc((size_t)8192 * 20 * 80 * 2);   // y2 / y4
    float* z1      = (float*)alloc((size_t)81920 * 4);
    float* partial = (float*)alloc((size_t)81920 * 4);
    int*   wp1 = (int*)alloc(64);   int* wp2 = (int*)alloc(256);
    int*   wp3 = (int*)alloc(256);  int* wp4 = (int*)alloc(1024);
    int*   wp5 = (int*)alloc(2048);
    float* tr2 = (float*)alloc(256); float* tr3 = (float*)alloc(256);
    float* tr4 = (float*)alloc(256); float* tr5 = (float*)alloc(256);
    float* tr6 = (float*)alloc(256);

    const int B = 8192;

    pack_k<<<1, 256, 0, stream>>>(w1, w2, w3, w4, w5, wp1, wp2, wp3, wp4, wp5);

    // conv1: (B,1,1250) f32 -> (B,3,624p) ; P=8, R=3, grid 2731
    {
        int grid = (B + 2) / 3;
        conv_k<1, 3, 6, 1252, 623, 624, 8, 3, true, 1250>
            <<<grid, 256, 0, stream>>>(x, wp1, nullptr, SA, partial, B);
        finalize_k<<<3, 256, 0, stream>>>(partial, grid, 3, (double)B * 623.0, g[0], bb[0], tr2);
    }
    // conv2: (B,3,624p) -> (B,5,312p) ; P=8, R=6, grid 1366
    {
        int grid = (B + 5) / 6;
        conv_k<3, 5, 5, 624, 310, 312, 8, 6, false>
            <<<grid, 256, 0, stream>>>(SA, wp2, tr2, SB, partial, B);
        finalize_k<<<5, 256, 0, stream>>>(partial, grid, 5, (double)B * 310.0, g[1], bb[1], tr3);
    }
    // conv3: (B,5,312p) -> (B,10,160p) ; P=4, R=6, grid 1366
    {
        int grid = (B + 5) / 6;
        conv_k<5, 10, 4, 312, 154, 160, 4, 6, false>
            <<<grid, 256, 0, stream>>>(SB, wp3, tr3, SA, partial, B);
        finalize_k<<<10, 256, 0, stream>>>(partial, grid, 10, (double)B * 154.0, g[2], bb[2], tr4);
    }
    // conv4: (B,10,160p) -> (B,20,80p) ; P=2, R=7, grid 1171
    {
        int grid = (B + 6) / 7;
        conv_k<10, 20, 4, 160, 76, 80, 2, 7, false>
            <<<grid, 256, 0, stream>>>(SA, wp4, tr4, SB, partial, B);
        finalize_k<<<20, 256, 0, stream>>>(partial, grid, 20, (double)B * 76.0, g[3], bb[3], tr5);
    }
    // conv5: (B,20,80p) -> (B,20,40p) ; P=1, R=7, grid 1171
    {
        int grid = (B + 6) / 7;
        conv_k<20, 20, 4, 80, 37, 40, 1, 7, false>
            <<<grid, 256, 0, stream>>>(SB, wp5, tr5, SA, partial, B);
        finalize_k<<<20, 256, 0, stream>>>(partial, grid, 20, (double)B * 37.0, g[4], bb[4], tr6);
    }
    // fc1: (B,740) @ (10,740)^T
    {
        int grid = 512;
        fc1_k<<<grid, 256, 0, stream>>>(SA, fw1, tr6, z1, partial, B);
    }
    // fc2 + finalize(fc1) + stats + apply, fused single block
    fc2_fused_k<<<1, 256, 0, stream>>>(z1, fw2, partial, 512,
                                       g[5], bb[5], g[6], bb[6],
                                       (float*)d_out, B);
}